// Round 1
// baseline (654.129 us; speedup 1.0000x reference)
//
#include <hip/hip_runtime.h>
#include <hip/hip_bf16.h>
#include <stdint.h>

#define HD 256
#define BM 64
#define BK 32
#define PAD 8

typedef __bf16 bf16x8 __attribute__((ext_vector_type(8)));
typedef float f32x4 __attribute__((ext_vector_type(4)));
typedef unsigned short ushort8 __attribute__((ext_vector_type(8)));

__device__ __forceinline__ unsigned short f2bf(float f) {
    unsigned int x = __float_as_uint(f);
    unsigned int r = (x + 0x7FFFu + ((x >> 16) & 1u)) >> 16;
    return (unsigned short)r;
}

// ---------------- prefix scan of seq_len -> offsets[B+1] ----------------
__global__ void scan_kernel(const int* __restrict__ seq_len, int* __restrict__ offsets, int B) {
    __shared__ int sums[256];
    int tid = threadIdx.x;
    int per = (B + 255) / 256;            // 16 for B=4096
    int b0 = tid * per;
    int local[32];
    int tot = 0;
    for (int i = 0; i < per && i < 32; ++i) {
        int b = b0 + i;
        int v = (b < B) ? seq_len[b] : 0;
        local[i] = tot;
        tot += v;
    }
    sums[tid] = tot;
    __syncthreads();
    for (int off = 1; off < 256; off <<= 1) {
        int v = (tid >= off) ? sums[tid - off] : 0;
        __syncthreads();
        sums[tid] += v;
        __syncthreads();
    }
    int start = sums[tid] - tot;          // exclusive prefix of this chunk
    for (int i = 0; i < per && i < 32; ++i) {
        int b = b0 + i;
        if (b < B) offsets[b] = start + local[i];
    }
    if (tid == 255) offsets[B] = sums[255];
}

// ---------------- seg id per token ----------------
__global__ void seg_kernel(const int* __restrict__ offsets, int* __restrict__ seg) {
    int b = blockIdx.x;
    int s = offsets[b], e = offsets[b + 1];
    for (int t = s + threadIdx.x; t < e; t += blockDim.x) seg[t] = b;
}

// ---------------- per-session mean ----------------
__global__ void mean_kernel(const float* __restrict__ hidden, const int* __restrict__ offsets,
                            float* __restrict__ mean) {
    int b = blockIdx.x;
    int s = offsets[b], e = offsets[b + 1];
    int tid = threadIdx.x;
    int g = tid >> 6, c = tid & 63;
    float4 acc = {0.f, 0.f, 0.f, 0.f};
    for (int t = s + g; t < e; t += 4) {
        const float4 v = *reinterpret_cast<const float4*>(hidden + (size_t)t * HD + c * 4);
        acc.x += v.x; acc.y += v.y; acc.z += v.z; acc.w += v.w;
    }
    __shared__ float4 part[4][64];
    part[g][c] = acc;
    __syncthreads();
    if (g == 0) {
        float4 a0 = part[0][c], a1 = part[1][c], a2 = part[2][c], a3 = part[3][c];
        float inv = 1.0f / (float)(e - s);
        float4 m;
        m.x = (a0.x + a1.x + a2.x + a3.x) * inv;
        m.y = (a0.y + a1.y + a2.y + a3.y) * inv;
        m.z = (a0.z + a1.z + a2.z + a3.z) * inv;
        m.w = (a0.w + a1.w + a2.w + a3.w) * inv;
        *reinterpret_cast<float4*>(mean + (size_t)b * HD + c * 4) = m;
    }
}

// ---------------- transpose+convert weights to bf16 [N][K] ----------------
__global__ void transpose_kernel(const float* __restrict__ Wp, const float* __restrict__ W1,
                                 const float* __restrict__ W2,
                                 unsigned short* __restrict__ WphT, unsigned short* __restrict__ WpbT,
                                 unsigned short* __restrict__ W1T, unsigned short* __restrict__ W2T) {
    int n = blockIdx.x;
    int k = threadIdx.x;
    WphT[n * HD + k] = f2bf(Wp[k * HD + n]);
    WpbT[n * HD + k] = f2bf(Wp[(HD + k) * HD + n]);
    W1T[n * HD + k]  = f2bf(W1[k * HD + n]);
    W2T[n * HD + k]  = f2bf(W2[k * HD + n]);
}

// ---------------- generic small GEMM: out[M,256] = A[M,256] @ B + bias1 (+bias2) ----------------
__global__ __launch_bounds__(256) void gemm_bias_kernel(
    const float* __restrict__ A, int M,
    const unsigned short* __restrict__ BT,        // bf16, [N=256][K=256]
    const float* __restrict__ bias1, const float* __restrict__ bias2,
    float* __restrict__ out) {
    __shared__ __align__(16) unsigned short As[BM][BK + PAD];
    __shared__ __align__(16) unsigned short Bs[HD][BK + PAD];
    int tid = threadIdx.x;
    int m0 = blockIdx.x * BM;
    int wave = tid >> 6, lane = tid & 63, quad = lane >> 4, cc = lane & 15;
    int nb = wave * 64;
    f32x4 acc[4][4];
    for (int i = 0; i < 4; ++i) for (int j = 0; j < 4; ++j) acc[i][j] = (f32x4){0.f, 0.f, 0.f, 0.f};
    int arow = tid >> 2, acg = (tid & 3) * 8;

    for (int kc = 0; kc < HD; kc += BK) {
        {   // stage A (fp32 -> bf16)
            int m = m0 + arow;
            float4 f0 = {0,0,0,0}, f1 = {0,0,0,0};
            if (m < M) {
                const float4* p = reinterpret_cast<const float4*>(A + (size_t)m * HD + kc + acg);
                f0 = p[0]; f1 = p[1];
            }
            ushort8 pk;
            pk[0] = f2bf(f0.x); pk[1] = f2bf(f0.y); pk[2] = f2bf(f0.z); pk[3] = f2bf(f0.w);
            pk[4] = f2bf(f1.x); pk[5] = f2bf(f1.y); pk[6] = f2bf(f1.z); pk[7] = f2bf(f1.w);
            *reinterpret_cast<ushort8*>(&As[arow][acg]) = pk;
        }
        for (int i = 0; i < 4; ++i) {   // stage B (already bf16, transposed)
            int n = i * 64 + (tid >> 2);
            int c8 = (tid & 3) * 8;
            ushort8 v = *reinterpret_cast<const ushort8*>(BT + (size_t)n * HD + kc + c8);
            *reinterpret_cast<ushort8*>(&Bs[n][c8]) = v;
        }
        __syncthreads();
        bf16x8 af[4], bfr[4];
        for (int mf = 0; mf < 4; ++mf) af[mf] = *reinterpret_cast<const bf16x8*>(&As[mf * 16 + cc][quad * 8]);
        for (int nf = 0; nf < 4; ++nf) bfr[nf] = *reinterpret_cast<const bf16x8*>(&Bs[nb + nf * 16 + cc][quad * 8]);
        for (int mf = 0; mf < 4; ++mf)
            for (int nf = 0; nf < 4; ++nf)
                acc[mf][nf] = __builtin_amdgcn_mfma_f32_16x16x32_bf16(af[mf], bfr[nf], acc[mf][nf], 0, 0, 0);
        __syncthreads();
    }
    for (int mf = 0; mf < 4; ++mf)
        for (int nf = 0; nf < 4; ++nf)
            for (int r = 0; r < 4; ++r) {
                int row = m0 + mf * 16 + quad * 4 + r;
                int col = nb + nf * 16 + cc;
                if (row < M) {
                    float v = acc[mf][nf][r] + bias1[col];
                    if (bias2) v += bias2[col];
                    out[(size_t)row * HD + col] = v;
                }
            }
}

// ---------------- fused main kernel: GEMM1+tanh -> LDS -> GEMM2+sigmoid -> alpha ----------------
__global__ __launch_bounds__(256) void main_kernel(
    const float* __restrict__ hidden, int T,
    const unsigned short* __restrict__ WphT,
    const unsigned short* __restrict__ W2T,
    const float* __restrict__ P2,
    const float* __restrict__ u,
    const float* __restrict__ qw, const float* __restrict__ qb,
    const int* __restrict__ rp, const int* __restrict__ seg,
    float* __restrict__ alpha) {
    __shared__ __align__(16) unsigned short As[BM][BK + PAD];        // 5 KB
    __shared__ __align__(16) unsigned short Bs[HD][BK + PAD];        // 20 KB
    __shared__ __align__(16) unsigned short Ph[BM][HD + PAD];        // 33 KB
    __shared__ int rp_s[BM];
    __shared__ int seg_s[BM];
    __shared__ float alpha_s[BM];

    int tid = threadIdx.x;
    int t0 = blockIdx.x * BM;
    if (tid < BM) {
        int t = t0 + tid;
        rp_s[tid]  = (t < T) ? rp[t] : 0;
        seg_s[tid] = (t < T) ? seg[t] : 0;
        alpha_s[tid] = qb[0];
    }
    int wave = tid >> 6, lane = tid & 63, quad = lane >> 4, cc = lane & 15;
    int nb = wave * 64;
    f32x4 acc[4][4];
    for (int i = 0; i < 4; ++i) for (int j = 0; j < 4; ++j) acc[i][j] = (f32x4){0.f, 0.f, 0.f, 0.f};
    int arow = tid >> 2, acg = (tid & 3) * 8;

    // ---- GEMM1: hidden @ WphT ----
    for (int kc = 0; kc < HD; kc += BK) {
        {
            int t = t0 + arow;
            float4 f0 = {0,0,0,0}, f1 = {0,0,0,0};
            if (t < T) {
                const float4* p = reinterpret_cast<const float4*>(hidden + (size_t)t * HD + kc + acg);
                f0 = p[0]; f1 = p[1];
            }
            ushort8 pk;
            pk[0] = f2bf(f0.x); pk[1] = f2bf(f0.y); pk[2] = f2bf(f0.z); pk[3] = f2bf(f0.w);
            pk[4] = f2bf(f1.x); pk[5] = f2bf(f1.y); pk[6] = f2bf(f1.z); pk[7] = f2bf(f1.w);
            *reinterpret_cast<ushort8*>(&As[arow][acg]) = pk;
        }
        for (int i = 0; i < 4; ++i) {
            int n = i * 64 + (tid >> 2);
            int c8 = (tid & 3) * 8;
            ushort8 v = *reinterpret_cast<const ushort8*>(WphT + (size_t)n * HD + kc + c8);
            *reinterpret_cast<ushort8*>(&Bs[n][c8]) = v;
        }
        __syncthreads();
        bf16x8 af[4], bfr[4];
        for (int mf = 0; mf < 4; ++mf) af[mf] = *reinterpret_cast<const bf16x8*>(&As[mf * 16 + cc][quad * 8]);
        for (int nf = 0; nf < 4; ++nf) bfr[nf] = *reinterpret_cast<const bf16x8*>(&Bs[nb + nf * 16 + cc][quad * 8]);
        for (int mf = 0; mf < 4; ++mf)
            for (int nf = 0; nf < 4; ++nf)
                acc[mf][nf] = __builtin_amdgcn_mfma_f32_16x16x32_bf16(af[mf], bfr[nf], acc[mf][nf], 0, 0, 0);
        __syncthreads();
    }

    // ---- epilogue 1: Ph = tanh(acc + P2[rp]) -> LDS (bf16); re-zero acc ----
    for (int mf = 0; mf < 4; ++mf)
        for (int nf = 0; nf < 4; ++nf)
            for (int r = 0; r < 4; ++r) {
                int row = mf * 16 + quad * 4 + r;
                int col = nb + nf * 16 + cc;
                float v = acc[mf][nf][r] + P2[(size_t)rp_s[row] * HD + col];
                Ph[row][col] = f2bf(tanhf(v));
                acc[mf][nf][r] = 0.f;
            }
    __syncthreads();

    // ---- GEMM2: Ph @ W2T (A straight from LDS) ----
    for (int kc = 0; kc < HD; kc += BK) {
        for (int i = 0; i < 4; ++i) {
            int n = i * 64 + (tid >> 2);
            int c8 = (tid & 3) * 8;
            ushort8 v = *reinterpret_cast<const ushort8*>(W2T + (size_t)n * HD + kc + c8);
            *reinterpret_cast<ushort8*>(&Bs[n][c8]) = v;
        }
        __syncthreads();
        bf16x8 af[4], bfr[4];
        for (int mf = 0; mf < 4; ++mf) af[mf] = *reinterpret_cast<const bf16x8*>(&Ph[mf * 16 + cc][kc + quad * 8]);
        for (int nf = 0; nf < 4; ++nf) bfr[nf] = *reinterpret_cast<const bf16x8*>(&Bs[nb + nf * 16 + cc][quad * 8]);
        for (int mf = 0; mf < 4; ++mf)
            for (int nf = 0; nf < 4; ++nf)
                acc[mf][nf] = __builtin_amdgcn_mfma_f32_16x16x32_bf16(af[mf], bfr[nf], acc[mf][nf], 0, 0, 0);
        __syncthreads();
    }

    // ---- epilogue 2: gate=sigmoid(acc+u[seg]); alpha partial = sum gate*qw ----
    float qwv[4];
    for (int nf = 0; nf < 4; ++nf) qwv[nf] = qw[nb + nf * 16 + cc];
    for (int mf = 0; mf < 4; ++mf)
        for (int r = 0; r < 4; ++r) {
            int row = mf * 16 + quad * 4 + r;
            const float* urow = u + (size_t)seg_s[row] * HD;
            float s = 0.f;
            for (int nf = 0; nf < 4; ++nf) {
                float g = acc[mf][nf][r] + urow[nb + nf * 16 + cc];
                g = 1.0f / (1.0f + __expf(-g));
                s += g * qwv[nf];
            }
            s += __shfl_xor(s, 1);
            s += __shfl_xor(s, 2);
            s += __shfl_xor(s, 4);
            s += __shfl_xor(s, 8);
            if (cc == 0) atomicAdd(&alpha_s[row], s);
        }
    __syncthreads();
    if (tid < BM) {
        int t = t0 + tid;
        if (t < T) alpha[t] = alpha_s[tid];
    }
}

// ---------------- weighted segment sum -> d_out ----------------
__global__ void hs_kernel(const float* __restrict__ hidden, const float* __restrict__ alpha,
                          const int* __restrict__ offsets, float* __restrict__ out) {
    int b = blockIdx.x;
    int s = offsets[b], e = offsets[b + 1];
    int tid = threadIdx.x;
    __shared__ float al[256];
    for (int i = tid; i < e - s; i += 256) al[i] = alpha[s + i];
    __syncthreads();
    int g = tid >> 6, c = tid & 63;
    float4 acc = {0.f, 0.f, 0.f, 0.f};
    for (int t = s + g; t < e; t += 4) {
        float a = al[t - s];
        const float4 v = *reinterpret_cast<const float4*>(hidden + (size_t)t * HD + c * 4);
        acc.x += a * v.x; acc.y += a * v.y; acc.z += a * v.z; acc.w += a * v.w;
    }
    __shared__ float4 part[4][64];
    part[g][c] = acc;
    __syncthreads();
    if (g == 0) {
        float4 a0 = part[0][c], a1 = part[1][c], a2 = part[2][c], a3 = part[3][c];
        float4 m;
        m.x = a0.x + a1.x + a2.x + a3.x;
        m.y = a0.y + a1.y + a2.y + a3.y;
        m.z = a0.z + a1.z + a2.z + a3.z;
        m.w = a0.w + a1.w + a2.w + a3.w;
        *reinterpret_cast<float4*>(out + (size_t)b * HD + c * 4) = m;
    }
}

extern "C" void kernel_launch(void* const* d_in, const int* in_sizes, int n_in,
                              void* d_out, int out_size, void* d_ws, size_t ws_size,
                              hipStream_t stream) {
    (void)n_in; (void)out_size; (void)ws_size;
    const float* hidden    = (const float*)d_in[0];
    const float* pos_table = (const float*)d_in[1];
    const float* W_pos     = (const float*)d_in[2];
    const float* b_pos     = (const float*)d_in[3];
    const float* W1        = (const float*)d_in[4];
    const float* b1        = (const float*)d_in[5];
    const float* W2        = (const float*)d_in[6];
    const float* b2        = (const float*)d_in[7];
    const float* qw        = (const float*)d_in[8];
    const float* qb        = (const float*)d_in[9];
    const int* seq_len     = (const int*)d_in[10];
    const int* reverse_pos = (const int*)d_in[11];

    int T  = in_sizes[0] / HD;
    int B  = in_sizes[10];
    int NP = in_sizes[1] / HD;   // 201

    char* ws = (char*)d_ws;
    auto carve = [&](size_t bytes) -> char* {
        char* p = ws;
        ws += (bytes + 255) & ~(size_t)255;
        return p;
    };
    int* offsets         = (int*)carve((size_t)(B + 1) * sizeof(int));
    int* seg             = (int*)carve((size_t)T * sizeof(int));
    float* mean          = (float*)carve((size_t)B * HD * sizeof(float));
    float* u             = (float*)carve((size_t)B * HD * sizeof(float));
    float* P2            = (float*)carve((size_t)NP * HD * sizeof(float));
    unsigned short* WphT = (unsigned short*)carve((size_t)HD * HD * 2);
    unsigned short* WpbT = (unsigned short*)carve((size_t)HD * HD * 2);
    unsigned short* W1T  = (unsigned short*)carve((size_t)HD * HD * 2);
    unsigned short* W2T  = (unsigned short*)carve((size_t)HD * HD * 2);
    float* alpha         = (float*)carve((size_t)T * sizeof(float));

    scan_kernel<<<1, 256, 0, stream>>>(seq_len, offsets, B);
    seg_kernel<<<B, 64, 0, stream>>>(offsets, seg);
    mean_kernel<<<B, 256, 0, stream>>>(hidden, offsets, mean);
    transpose_kernel<<<HD, HD, 0, stream>>>(W_pos, W1, W2, WphT, WpbT, W1T, W2T);
    gemm_bias_kernel<<<(NP + BM - 1) / BM, 256, 0, stream>>>(pos_table, NP, WpbT, b_pos, nullptr, P2);
    gemm_bias_kernel<<<(B + BM - 1) / BM, 256, 0, stream>>>(mean, B, W1T, b1, b2, u);
    main_kernel<<<(T + BM - 1) / BM, 256, 0, stream>>>(hidden, T, WphT, W2T, P2, u, qw, qb,
                                                       reverse_pos, seg, alpha);
    hs_kernel<<<B, 256, 0, stream>>>(hidden, alpha, offsets, (float*)d_out);
}

// Round 3
// 594.221 us; speedup vs baseline: 1.1008x; 1.1008x over previous
//
#include <hip/hip_runtime.h>
#include <hip/hip_bf16.h>
#include <stdint.h>

#define HD 256
#define BM 64
#define BK 32
#define APAD 8
#define ASTRIDE (HD + APAD)   // 264 ushorts; 528 B = 132 banks == 4 mod 32

typedef __bf16 bf16x8 __attribute__((ext_vector_type(8)));
typedef float f32x4 __attribute__((ext_vector_type(4)));
typedef unsigned short ushort8v __attribute__((ext_vector_type(8)));
typedef unsigned short us4 __attribute__((ext_vector_type(4)));

__device__ __forceinline__ unsigned short f2bf(float f) {
    unsigned int x = __float_as_uint(f);
    unsigned int r = (x + 0x7FFFu + ((x >> 16) & 1u)) >> 16;
    return (unsigned short)r;
}

// ---------------- prefix scan of seq_len -> offsets[B+1] ----------------
__global__ void scan_kernel(const int* __restrict__ seq_len, int* __restrict__ offsets, int B) {
    __shared__ int sums[256];
    int tid = threadIdx.x;
    int per = (B + 255) / 256;
    int b0 = tid * per;
    int local[32];
    int tot = 0;
    for (int i = 0; i < per && i < 32; ++i) {
        int b = b0 + i;
        int v = (b < B) ? seq_len[b] : 0;
        local[i] = tot;
        tot += v;
    }
    sums[tid] = tot;
    __syncthreads();
    for (int off = 1; off < 256; off <<= 1) {
        int v = (tid >= off) ? sums[tid - off] : 0;
        __syncthreads();
        sums[tid] += v;
        __syncthreads();
    }
    int start = sums[tid] - tot;
    for (int i = 0; i < per && i < 32; ++i) {
        int b = b0 + i;
        if (b < B) offsets[b] = start + local[i];
    }
    if (tid == 255) offsets[B] = sums[255];
}

// ---------------- per-session mean (+ seg fill fused) ----------------
__global__ void mean_kernel(const float* __restrict__ hidden, const int* __restrict__ offsets,
                            float* __restrict__ mean, int* __restrict__ seg) {
    int b = blockIdx.x;
    int s = offsets[b], e = offsets[b + 1];
    int tid = threadIdx.x;
    for (int t = s + tid; t < e; t += 256) seg[t] = b;
    int g = tid >> 6, c = tid & 63;
    float4 acc = {0.f, 0.f, 0.f, 0.f};
    for (int t = s + g; t < e; t += 4) {
        const float4 v = *reinterpret_cast<const float4*>(hidden + (size_t)t * HD + c * 4);
        acc.x += v.x; acc.y += v.y; acc.z += v.z; acc.w += v.w;
    }
    __shared__ float4 part[4][64];
    part[g][c] = acc;
    __syncthreads();
    if (g == 0) {
        float4 a0 = part[0][c], a1 = part[1][c], a2 = part[2][c], a3 = part[3][c];
        float inv = 1.0f / (float)(e - s);
        float4 m;
        m.x = (a0.x + a1.x + a2.x + a3.x) * inv;
        m.y = (a0.y + a1.y + a2.y + a3.y) * inv;
        m.z = (a0.z + a1.z + a2.z + a3.z) * inv;
        m.w = (a0.w + a1.w + a2.w + a3.w) * inv;
        *reinterpret_cast<float4*>(mean + (size_t)b * HD + c * 4) = m;
    }
}

// ---------------- transpose+convert weights to bf16 [N][K] ----------------
__global__ void transpose_kernel(const float* __restrict__ Wp, const float* __restrict__ W1,
                                 const float* __restrict__ W2,
                                 unsigned short* __restrict__ WphT, unsigned short* __restrict__ WpbT,
                                 unsigned short* __restrict__ W1T, unsigned short* __restrict__ W2T) {
    int n = blockIdx.x;
    int k = threadIdx.x;
    WphT[n * HD + k] = f2bf(Wp[k * HD + n]);
    WpbT[n * HD + k] = f2bf(Wp[(HD + k) * HD + n]);
    W1T[n * HD + k]  = f2bf(W1[k * HD + n]);
    W2T[n * HD + k]  = f2bf(W2[k * HD + n]);
}

// ---------------- small GEMM: out[M,256] = A[M,256] @ BT^T + bias1 (+bias2) ----------------
__global__ __launch_bounds__(256) void gemm_bias_kernel(
    const float* __restrict__ A, int M,
    const unsigned short* __restrict__ BT,
    const float* __restrict__ bias1, const float* __restrict__ bias2,
    float* __restrict__ out) {
    __shared__ __align__(16) unsigned short As[BM][ASTRIDE];
    int tid = threadIdx.x;
    int m0 = blockIdx.x * BM;
    int wave = tid >> 6, lane = tid & 63, quad = lane >> 4, cc = lane & 15;
    int nb = wave * 64;
    f32x4 acc[4][4];
    for (int i = 0; i < 4; ++i) for (int j = 0; j < 4; ++j) acc[i][j] = (f32x4){0.f, 0.f, 0.f, 0.f};

    // stage full A tile (fp32->bf16) into LDS
    {
        int row = tid >> 2;
        int m = m0 + row;
        for (int i = 0; i < 8; ++i) {
            int cg = ((tid & 3) + 4 * i) * 8;
            float4 f0 = {0,0,0,0}, f1 = {0,0,0,0};
            if (m < M) {
                const float4* p = reinterpret_cast<const float4*>(A + (size_t)m * HD + cg);
                f0 = p[0]; f1 = p[1];
            }
            ushort8v pk;
            pk[0] = f2bf(f0.x); pk[1] = f2bf(f0.y); pk[2] = f2bf(f0.z); pk[3] = f2bf(f0.w);
            pk[4] = f2bf(f1.x); pk[5] = f2bf(f1.y); pk[6] = f2bf(f1.z); pk[7] = f2bf(f1.w);
            *reinterpret_cast<ushort8v*>(&As[row][cg]) = pk;
        }
    }
    __syncthreads();

    for (int kc = 0; kc < HD; kc += BK) {
        bf16x8 bfr[4];
        for (int nf = 0; nf < 4; ++nf)
            bfr[nf] = *reinterpret_cast<const bf16x8*>(BT + (size_t)(nb + nf * 16 + cc) * HD + kc + quad * 8);
        for (int mf = 0; mf < 4; ++mf) {
            bf16x8 af = *reinterpret_cast<const bf16x8*>(&As[mf * 16 + cc][kc + quad * 8]);
            for (int nf = 0; nf < 4; ++nf)
                acc[mf][nf] = __builtin_amdgcn_mfma_f32_16x16x32_bf16(af, bfr[nf], acc[mf][nf], 0, 0, 0);
        }
    }
    for (int mf = 0; mf < 4; ++mf)
        for (int nf = 0; nf < 4; ++nf)
            for (int r = 0; r < 4; ++r) {
                int row = m0 + mf * 16 + quad * 4 + r;
                int col = nb + nf * 16 + cc;
                if (row < M) {
                    float v = acc[mf][nf][r] + bias1[col];
                    if (bias2) v += bias2[col];
                    out[(size_t)row * HD + col] = v;
                }
            }
}

// ---------------- fused main kernel ----------------
// GEMM1 computed transposed: D1[h][token] = Wph^T x hidden-tile  (A=WphT global frags,
// B=token frags from LDS). C-layout then gives each lane 4 consecutive h for one token,
// so tanh-epilogue writes Ph[token][h] with ds_write_b64, in place over the A buffer.
// GEMM2: D2[token][n] = Ph x W2 (A=Ph frags from LDS, B=W2T global frags).
__global__ __launch_bounds__(256, 4) void main_kernel(
    const float* __restrict__ hidden, int T,
    const unsigned short* __restrict__ WphT,
    const unsigned short* __restrict__ W2T,
    const float* __restrict__ P2,
    const float* __restrict__ u,
    const float* __restrict__ qw, const float* __restrict__ qb,
    const int* __restrict__ rp, const int* __restrict__ seg,
    float* __restrict__ alpha) {
    __shared__ __align__(16) unsigned short Ah[BM][ASTRIDE];   // 33.8 KB: A tile, then Ph in place
    __shared__ int rp_s[BM];
    __shared__ int seg_s[BM];
    __shared__ float alpha_s[BM];

    int tid = threadIdx.x;
    int t0 = blockIdx.x * BM;
    int wave = tid >> 6, lane = tid & 63, quad = lane >> 4, cc = lane & 15;
    int mb = wave * 64;   // GEMM1: h-slice ; GEMM2: n-slice

    // ---- stage hidden tile -> bf16 LDS; small per-token metadata ----
    {
        int row = tid >> 2;
        int t = t0 + row;
        for (int i = 0; i < 8; ++i) {
            int cg = ((tid & 3) + 4 * i) * 8;
            float4 f0 = {0,0,0,0}, f1 = {0,0,0,0};
            if (t < T) {
                const float4* p = reinterpret_cast<const float4*>(hidden + (size_t)t * HD + cg);
                f0 = p[0]; f1 = p[1];
            }
            ushort8v pk;
            pk[0] = f2bf(f0.x); pk[1] = f2bf(f0.y); pk[2] = f2bf(f0.z); pk[3] = f2bf(f0.w);
            pk[4] = f2bf(f1.x); pk[5] = f2bf(f1.y); pk[6] = f2bf(f1.z); pk[7] = f2bf(f1.w);
            *reinterpret_cast<ushort8v*>(&Ah[row][cg]) = pk;
        }
    }
    if (tid < BM) {
        int t = t0 + tid;
        rp_s[tid]  = (t < T) ? rp[t] : 0;
        seg_s[tid] = (t < T) ? seg[t] : 0;
        alpha_s[tid] = qb[0];
    }
    __syncthreads();

    f32x4 acc[4][4];
    for (int i = 0; i < 4; ++i) for (int j = 0; j < 4; ++j) acc[i][j] = (f32x4){0.f, 0.f, 0.f, 0.f};

    // ---- GEMM1 (transposed): rows = h (mb+mf*16+..), cols = token ----
    for (int kc = 0; kc < HD; kc += BK) {
        bf16x8 bfr[4];
        for (int nf = 0; nf < 4; ++nf)   // token frags from LDS
            bfr[nf] = *reinterpret_cast<const bf16x8*>(&Ah[nf * 16 + cc][kc + quad * 8]);
        for (int mf = 0; mf < 4; ++mf) {
            bf16x8 af = *reinterpret_cast<const bf16x8*>(WphT + (size_t)(mb + mf * 16 + cc) * HD + kc + quad * 8);
            for (int nf = 0; nf < 4; ++nf)
                acc[mf][nf] = __builtin_amdgcn_mfma_f32_16x16x32_bf16(af, bfr[nf], acc[mf][nf], 0, 0, 0);
        }
    }
    __syncthreads();   // all LDS reads of the A tile done

    // ---- epilogue 1: Ph[token][h] = tanh(acc + P2[rp][h]), packed b64 writes ----
    for (int mf = 0; mf < 4; ++mf)
        for (int nf = 0; nf < 4; ++nf) {
            int token = nf * 16 + cc;
            int h0 = mb + mf * 16 + quad * 4;
            const float4 p2v = *reinterpret_cast<const float4*>(P2 + (size_t)rp_s[token] * HD + h0);
            us4 pk;
            {
                float v0 = acc[mf][nf][0] + p2v.x;
                float v1 = acc[mf][nf][1] + p2v.y;
                float v2 = acc[mf][nf][2] + p2v.z;
                float v3 = acc[mf][nf][3] + p2v.w;
                float e0 = __expf(2.f * v0), e1 = __expf(2.f * v1);
                float e2 = __expf(2.f * v2), e3 = __expf(2.f * v3);
                pk[0] = f2bf(1.f - 2.f / (e0 + 1.f));
                pk[1] = f2bf(1.f - 2.f / (e1 + 1.f));
                pk[2] = f2bf(1.f - 2.f / (e2 + 1.f));
                pk[3] = f2bf(1.f - 2.f / (e3 + 1.f));
            }
            *reinterpret_cast<us4*>(&Ah[token][h0]) = pk;
            acc[mf][nf] = (f32x4){0.f, 0.f, 0.f, 0.f};
        }
    __syncthreads();

    // ---- GEMM2: rows = token, cols = n (mb slice) ----
    for (int kc = 0; kc < HD; kc += BK) {
        bf16x8 bfr[4];
        for (int nf = 0; nf < 4; ++nf)   // W2 frags from global
            bfr[nf] = *reinterpret_cast<const bf16x8*>(W2T + (size_t)(mb + nf * 16 + cc) * HD + kc + quad * 8);
        for (int mf = 0; mf < 4; ++mf) {
            bf16x8 af = *reinterpret_cast<const bf16x8*>(&Ah[mf * 16 + cc][kc + quad * 8]);
            for (int nf = 0; nf < 4; ++nf)
                acc[mf][nf] = __builtin_amdgcn_mfma_f32_16x16x32_bf16(af, bfr[nf], acc[mf][nf], 0, 0, 0);
        }
    }

    // ---- epilogue 2: alpha partial = sum_n sigmoid(acc + u[seg][n]) * qw[n] ----
    float qwv[4];
    for (int nf = 0; nf < 4; ++nf) qwv[nf] = qw[mb + nf * 16 + cc];
    for (int mf = 0; mf < 4; ++mf)
        for (int r = 0; r < 4; ++r) {
            int token = mf * 16 + quad * 4 + r;
            const float* urow = u + (size_t)seg_s[token] * HD;
            float s = 0.f;
            for (int nf = 0; nf < 4; ++nf) {
                float g = acc[mf][nf][r] + urow[mb + nf * 16 + cc];
                g = 1.0f / (1.0f + __expf(-g));
                s += g * qwv[nf];
            }
            s += __shfl_xor(s, 1);
            s += __shfl_xor(s, 2);
            s += __shfl_xor(s, 4);
            s += __shfl_xor(s, 8);
            if (cc == 0) atomicAdd(&alpha_s[token], s);
        }
    __syncthreads();
    if (tid < BM) {
        int t = t0 + tid;
        if (t < T) alpha[t] = alpha_s[tid];
    }
}

// ---------------- weighted segment sum -> d_out ----------------
__global__ void hs_kernel(const float* __restrict__ hidden, const float* __restrict__ alpha,
                          const int* __restrict__ offsets, float* __restrict__ out) {
    int b = blockIdx.x;
    int s = offsets[b], e = offsets[b + 1];
    int tid = threadIdx.x;
    __shared__ float al[256];
    for (int i = tid; i < e - s; i += 256) al[i] = alpha[s + i];
    __syncthreads();
    int g = tid >> 6, c = tid & 63;
    float4 acc = {0.f, 0.f, 0.f, 0.f};
    for (int t = s + g; t < e; t += 4) {
        float a = al[t - s];
        const float4 v = *reinterpret_cast<const float4*>(hidden + (size_t)t * HD + c * 4);
        acc.x += a * v.x; acc.y += a * v.y; acc.z += a * v.z; acc.w += a * v.w;
    }
    __shared__ float4 part[4][64];
    part[g][c] = acc;
    __syncthreads();
    if (g == 0) {
        float4 a0 = part[0][c], a1 = part[1][c], a2 = part[2][c], a3 = part[3][c];
        float4 m;
        m.x = a0.x + a1.x + a2.x + a3.x;
        m.y = a0.y + a1.y + a2.y + a3.y;
        m.z = a0.z + a1.z + a2.z + a3.z;
        m.w = a0.w + a1.w + a2.w + a3.w;
        *reinterpret_cast<float4*>(out + (size_t)b * HD + c * 4) = m;
    }
}

extern "C" void kernel_launch(void* const* d_in, const int* in_sizes, int n_in,
                              void* d_out, int out_size, void* d_ws, size_t ws_size,
                              hipStream_t stream) {
    (void)n_in; (void)out_size; (void)ws_size;
    const float* hidden    = (const float*)d_in[0];
    const float* pos_table = (const float*)d_in[1];
    const float* W_pos     = (const float*)d_in[2];
    const float* b_pos     = (const float*)d_in[3];
    const float* W1        = (const float*)d_in[4];
    const float* b1        = (const float*)d_in[5];
    const float* W2        = (const float*)d_in[6];
    const float* b2        = (const float*)d_in[7];
    const float* qw        = (const float*)d_in[8];
    const float* qb        = (const float*)d_in[9];
    const int* seq_len     = (const int*)d_in[10];
    const int* reverse_pos = (const int*)d_in[11];

    int T  = in_sizes[0] / HD;
    int B  = in_sizes[10];
    int NP = in_sizes[1] / HD;

    char* ws = (char*)d_ws;
    auto carve = [&](size_t bytes) -> char* {
        char* p = ws;
        ws += (bytes + 255) & ~(size_t)255;
        return p;
    };
    int* offsets         = (int*)carve((size_t)(B + 1) * sizeof(int));
    int* seg             = (int*)carve((size_t)T * sizeof(int));
    float* mean          = (float*)carve((size_t)B * HD * sizeof(float));
    float* u             = (float*)carve((size_t)B * HD * sizeof(float));
    float* P2            = (float*)carve((size_t)NP * HD * sizeof(float));
    unsigned short* WphT = (unsigned short*)carve((size_t)HD * HD * 2);
    unsigned short* WpbT = (unsigned short*)carve((size_t)HD * HD * 2);
    unsigned short* W1T  = (unsigned short*)carve((size_t)HD * HD * 2);
    unsigned short* W2T  = (unsigned short*)carve((size_t)HD * HD * 2);
    float* alpha         = (float*)carve((size_t)T * sizeof(float));

    scan_kernel<<<1, 256, 0, stream>>>(seq_len, offsets, B);
    transpose_kernel<<<HD, HD, 0, stream>>>(W_pos, W1, W2, WphT, WpbT, W1T, W2T);
    mean_kernel<<<B, 256, 0, stream>>>(hidden, offsets, mean, seg);
    gemm_bias_kernel<<<(NP + BM - 1) / BM, 256, 0, stream>>>(pos_table, NP, WpbT, b_pos, nullptr, P2);
    gemm_bias_kernel<<<(B + BM - 1) / BM, 256, 0, stream>>>(mean, B, W1T, b1, b2, u);
    main_kernel<<<(T + BM - 1) / BM, 256, 0, stream>>>(hidden, T, WphT, W2T, P2, u, qw, qb,
                                                       reverse_pos, seg, alpha);
    hs_kernel<<<B, 256, 0, stream>>>(hidden, alpha, offsets, (float*)d_out);
}

// Round 4
// 575.530 us; speedup vs baseline: 1.1366x; 1.0325x over previous
//
#include <hip/hip_runtime.h>
#include <hip/hip_bf16.h>
#include <stdint.h>

#define HD 256
#define BM 64
#define APAD 8
#define ASTRIDE (HD + APAD)   // 264 ushorts

typedef __bf16 bf16x8 __attribute__((ext_vector_type(8)));
typedef float f32x4 __attribute__((ext_vector_type(4)));
typedef unsigned short ushort8v __attribute__((ext_vector_type(8)));
typedef unsigned short us4 __attribute__((ext_vector_type(4)));

__device__ __forceinline__ unsigned short f2bf(float f) {
    unsigned int x = __float_as_uint(f);
    unsigned int r = (x + 0x7FFFu + ((x >> 16) & 1u)) >> 16;
    return (unsigned short)r;
}

// ---------------- prefix scan of seq_len -> offsets[B+1] ----------------
__global__ void scan_kernel(const int* __restrict__ seq_len, int* __restrict__ offsets, int B) {
    __shared__ int sums[256];
    int tid = threadIdx.x;
    int per = (B + 255) / 256;
    int b0 = tid * per;
    int local[32];
    int tot = 0;
    for (int i = 0; i < per && i < 32; ++i) {
        int b = b0 + i;
        int v = (b < B) ? seq_len[b] : 0;
        local[i] = tot;
        tot += v;
    }
    sums[tid] = tot;
    __syncthreads();
    for (int off = 1; off < 256; off <<= 1) {
        int v = (tid >= off) ? sums[tid - off] : 0;
        __syncthreads();
        sums[tid] += v;
        __syncthreads();
    }
    int start = sums[tid] - tot;
    for (int i = 0; i < per && i < 32; ++i) {
        int b = b0 + i;
        if (b < B) offsets[b] = start + local[i];
    }
    if (tid == 255) offsets[B] = sums[255];
}

// ---------------- per-session mean + seg fill + bf16 hidden copy + bf16 mean ----------------
__global__ void mean_kernel(const float* __restrict__ hidden, const int* __restrict__ offsets,
                            unsigned short* __restrict__ mean_bf, unsigned short* __restrict__ hb,
                            int* __restrict__ seg) {
    int b = blockIdx.x;
    int s = offsets[b], e = offsets[b + 1];
    int tid = threadIdx.x;
    for (int t = s + tid; t < e; t += 256) seg[t] = b;
    int g = tid >> 6, c = tid & 63;
    float4 acc = {0.f, 0.f, 0.f, 0.f};
    for (int t = s + g; t < e; t += 4) {
        const float4 v = *reinterpret_cast<const float4*>(hidden + (size_t)t * HD + c * 4);
        acc.x += v.x; acc.y += v.y; acc.z += v.z; acc.w += v.w;
        if (hb) {
            us4 pk;
            pk[0] = f2bf(v.x); pk[1] = f2bf(v.y); pk[2] = f2bf(v.z); pk[3] = f2bf(v.w);
            *reinterpret_cast<us4*>(hb + (size_t)t * HD + c * 4) = pk;
        }
    }
    __shared__ float4 part[4][64];
    part[g][c] = acc;
    __syncthreads();
    if (g == 0) {
        float4 a0 = part[0][c], a1 = part[1][c], a2 = part[2][c], a3 = part[3][c];
        float inv = 1.0f / (float)(e - s);
        us4 pk;
        pk[0] = f2bf((a0.x + a1.x + a2.x + a3.x) * inv);
        pk[1] = f2bf((a0.y + a1.y + a2.y + a3.y) * inv);
        pk[2] = f2bf((a0.z + a1.z + a2.z + a3.z) * inv);
        pk[3] = f2bf((a0.w + a1.w + a2.w + a3.w) * inv);
        *reinterpret_cast<us4*>(mean_bf + (size_t)b * HD + c * 4) = pk;
    }
}

// ---------------- transpose+convert weights to bf16 [N][K] ----------------
__global__ void transpose_kernel(const float* __restrict__ Wp, const float* __restrict__ W1,
                                 const float* __restrict__ W2,
                                 unsigned short* __restrict__ WphT, unsigned short* __restrict__ WpbT,
                                 unsigned short* __restrict__ W1T, unsigned short* __restrict__ W2T) {
    int n = blockIdx.x;
    int k = threadIdx.x;
    WphT[n * HD + k] = f2bf(Wp[k * HD + n]);
    WpbT[n * HD + k] = f2bf(Wp[(HD + k) * HD + n]);
    W1T[n * HD + k]  = f2bf(W1[k * HD + n]);
    W2T[n * HD + k]  = f2bf(W2[k * HD + n]);
}

// ---------------- fused small GEMMs (u and P2), M-tile = 16 ----------------
// blocks [0, nbu): u[m] = mean_bf[m] @ W1T^T + b1 + b2
// blocks [nbu, nbu+nbp): P2[m] = pos_table[m] @ WpbT^T + b_pos
__global__ __launch_bounds__(256) void small_gemm_kernel(
    const unsigned short* __restrict__ mean_bf, int Mu, int nbu,
    const float* __restrict__ pos_table, int Mp,
    const unsigned short* __restrict__ W1T, const unsigned short* __restrict__ WpbT,
    const float* __restrict__ b1, const float* __restrict__ b2, const float* __restrict__ bp,
    float* __restrict__ u, float* __restrict__ P2) {
    __shared__ __align__(16) unsigned short As[16][ASTRIDE];
    int tid = threadIdx.x;
    bool isU = (int)blockIdx.x < nbu;
    int m0 = isU ? blockIdx.x * 16 : (blockIdx.x - nbu) * 16;
    int M  = isU ? Mu : Mp;
    const unsigned short* BT = isU ? W1T : WpbT;
    float* out = isU ? u : P2;

    {   // stage 16 rows x 256 cols
        int row = tid >> 4;
        int colg = (tid & 15) * 16;
        int m = m0 + row;
        if (isU) {
            ushort8v v0 = {0,0,0,0,0,0,0,0}, v1 = {0,0,0,0,0,0,0,0};
            if (m < M) {
                v0 = *reinterpret_cast<const ushort8v*>(mean_bf + (size_t)m * HD + colg);
                v1 = *reinterpret_cast<const ushort8v*>(mean_bf + (size_t)m * HD + colg + 8);
            }
            *reinterpret_cast<ushort8v*>(&As[row][colg])     = v0;
            *reinterpret_cast<ushort8v*>(&As[row][colg + 8]) = v1;
        } else {
            float4 f[4] = {{0,0,0,0},{0,0,0,0},{0,0,0,0},{0,0,0,0}};
            if (m < M) {
                const float4* p = reinterpret_cast<const float4*>(pos_table + (size_t)m * HD + colg);
                f[0] = p[0]; f[1] = p[1]; f[2] = p[2]; f[3] = p[3];
            }
            ushort8v v0, v1;
            v0[0]=f2bf(f[0].x); v0[1]=f2bf(f[0].y); v0[2]=f2bf(f[0].z); v0[3]=f2bf(f[0].w);
            v0[4]=f2bf(f[1].x); v0[5]=f2bf(f[1].y); v0[6]=f2bf(f[1].z); v0[7]=f2bf(f[1].w);
            v1[0]=f2bf(f[2].x); v1[1]=f2bf(f[2].y); v1[2]=f2bf(f[2].z); v1[3]=f2bf(f[2].w);
            v1[4]=f2bf(f[3].x); v1[5]=f2bf(f[3].y); v1[6]=f2bf(f[3].z); v1[7]=f2bf(f[3].w);
            *reinterpret_cast<ushort8v*>(&As[row][colg])     = v0;
            *reinterpret_cast<ushort8v*>(&As[row][colg + 8]) = v1;
        }
    }
    __syncthreads();

    int wave = tid >> 6, lane = tid & 63, quad = lane >> 4, cc = lane & 15;
    int nb = wave * 64;
    f32x4 acc4[4];
    for (int i = 0; i < 4; ++i) acc4[i] = (f32x4){0.f, 0.f, 0.f, 0.f};

    bf16x8 wfp[4];
    for (int nf = 0; nf < 4; ++nf)
        wfp[nf] = *reinterpret_cast<const bf16x8*>(BT + (size_t)(nb + nf * 16 + cc) * HD + quad * 8);
    for (int kc8 = 0; kc8 < 8; ++kc8) {
        int kc = kc8 * 32;
        bf16x8 wfc[4];
        for (int nf = 0; nf < 4; ++nf) wfc[nf] = wfp[nf];
        if (kc8 < 7)
            for (int nf = 0; nf < 4; ++nf)
                wfp[nf] = *reinterpret_cast<const bf16x8*>(BT + (size_t)(nb + nf * 16 + cc) * HD + kc + 32 + quad * 8);
        bf16x8 af = *reinterpret_cast<const bf16x8*>(&As[cc][kc + quad * 8]);
        for (int nf = 0; nf < 4; ++nf)
            acc4[nf] = __builtin_amdgcn_mfma_f32_16x16x32_bf16(af, wfc[nf], acc4[nf], 0, 0, 0);
    }
    for (int nf = 0; nf < 4; ++nf)
        for (int r = 0; r < 4; ++r) {
            int row = m0 + quad * 4 + r;
            int col = nb + nf * 16 + cc;
            if (row < M) {
                float bias = isU ? (b1[col] + b2[col]) : bp[col];
                out[(size_t)row * HD + col] = acc4[nf][r] + bias;
            }
        }
}

// ---------------- fused main kernel ----------------
__global__ __launch_bounds__(256, 3) void main_kernel(
    const float* __restrict__ hidden, const unsigned short* __restrict__ hb, int T,
    const unsigned short* __restrict__ WphT,
    const unsigned short* __restrict__ W2T,
    const float* __restrict__ P2,
    const float* __restrict__ u,
    const float* __restrict__ qw, const float* __restrict__ qb,
    const int* __restrict__ rp, const int* __restrict__ seg,
    float* __restrict__ alpha) {
    __shared__ __align__(16) unsigned short Ah[BM][ASTRIDE];   // A tile, then Ph in place
    __shared__ int rp_s[BM];
    __shared__ int seg_s[BM];
    __shared__ float alpha_s[BM];

    int tid = threadIdx.x;
    int t0 = blockIdx.x * BM;
    int wave = tid >> 6, lane = tid & 63, quad = lane >> 4, cc = lane & 15;
    int mb = wave * 64;

    // ---- preload GEMM1 weight frags for kc=0 (in flight during staging) ----
    bf16x8 afp[4];
    for (int mf = 0; mf < 4; ++mf)
        afp[mf] = *reinterpret_cast<const bf16x8*>(WphT + (size_t)(mb + mf * 16 + cc) * HD + quad * 8);

    // ---- stage hidden tile -> LDS ----
    {
        int row = tid >> 2;
        int t = t0 + row;
        if (hb) {
            for (int i = 0; i < 8; ++i) {
                int cg = (tid & 3) * 8 + 32 * i;
                ushort8v v = {0,0,0,0,0,0,0,0};
                if (t < T) v = *reinterpret_cast<const ushort8v*>(hb + (size_t)t * HD + cg);
                *reinterpret_cast<ushort8v*>(&Ah[row][cg]) = v;
            }
        } else {
            for (int i = 0; i < 8; ++i) {
                int cg = (tid & 3) * 8 + 32 * i;
                float4 f0 = {0,0,0,0}, f1 = {0,0,0,0};
                if (t < T) {
                    const float4* p = reinterpret_cast<const float4*>(hidden + (size_t)t * HD + cg);
                    f0 = p[0]; f1 = p[1];
                }
                ushort8v pk;
                pk[0] = f2bf(f0.x); pk[1] = f2bf(f0.y); pk[2] = f2bf(f0.z); pk[3] = f2bf(f0.w);
                pk[4] = f2bf(f1.x); pk[5] = f2bf(f1.y); pk[6] = f2bf(f1.z); pk[7] = f2bf(f1.w);
                *reinterpret_cast<ushort8v*>(&Ah[row][cg]) = pk;
            }
        }
    }
    if (tid < BM) {
        int t = t0 + tid;
        rp_s[tid]  = (t < T) ? rp[t] : 0;
        seg_s[tid] = (t < T) ? seg[t] : 0;
        alpha_s[tid] = qb[0];
    }
    __syncthreads();

    f32x4 acc[4][4];
    for (int i = 0; i < 4; ++i) for (int j = 0; j < 4; ++j) acc[i][j] = (f32x4){0.f, 0.f, 0.f, 0.f};

    // ---- GEMM1 (transposed): rows = h, cols = token; weights pipelined ----
    for (int kc8 = 0; kc8 < 8; ++kc8) {
        int kc = kc8 * 32;
        bf16x8 afc[4];
        for (int mf = 0; mf < 4; ++mf) afc[mf] = afp[mf];
        if (kc8 < 7)
            for (int mf = 0; mf < 4; ++mf)
                afp[mf] = *reinterpret_cast<const bf16x8*>(WphT + (size_t)(mb + mf * 16 + cc) * HD + kc + 32 + quad * 8);
        bf16x8 bfr[4];
        for (int nf = 0; nf < 4; ++nf)
            bfr[nf] = *reinterpret_cast<const bf16x8*>(&Ah[nf * 16 + cc][kc + quad * 8]);
        for (int mf = 0; mf < 4; ++mf)
            for (int nf = 0; nf < 4; ++nf)
                acc[mf][nf] = __builtin_amdgcn_mfma_f32_16x16x32_bf16(afc[mf], bfr[nf], acc[mf][nf], 0, 0, 0);
    }
    __syncthreads();   // all LDS reads of the A tile done

    // ---- preload GEMM2 weight frags kc=0 (fly during epilogue1) ----
    bf16x8 wfp[4];
    for (int nf = 0; nf < 4; ++nf)
        wfp[nf] = *reinterpret_cast<const bf16x8*>(W2T + (size_t)(mb + nf * 16 + cc) * HD + quad * 8);

    // ---- epilogue 1: Ph[token][h] = tanh(acc + P2[rp][h]) ----
    for (int mf = 0; mf < 4; ++mf)
        for (int nf = 0; nf < 4; ++nf) {
            int token = nf * 16 + cc;
            int h0 = mb + mf * 16 + quad * 4;
            const float4 p2v = *reinterpret_cast<const float4*>(P2 + (size_t)rp_s[token] * HD + h0);
            us4 pk;
            {
                float v0 = acc[mf][nf][0] + p2v.x;
                float v1 = acc[mf][nf][1] + p2v.y;
                float v2 = acc[mf][nf][2] + p2v.z;
                float v3 = acc[mf][nf][3] + p2v.w;
                float e0 = __expf(2.f * v0), e1 = __expf(2.f * v1);
                float e2 = __expf(2.f * v2), e3 = __expf(2.f * v3);
                pk[0] = f2bf(1.f - 2.f / (e0 + 1.f));
                pk[1] = f2bf(1.f - 2.f / (e1 + 1.f));
                pk[2] = f2bf(1.f - 2.f / (e2 + 1.f));
                pk[3] = f2bf(1.f - 2.f / (e3 + 1.f));
            }
            *reinterpret_cast<us4*>(&Ah[token][h0]) = pk;
            acc[mf][nf] = (f32x4){0.f, 0.f, 0.f, 0.f};
        }
    __syncthreads();

    // ---- GEMM2: rows = token, cols = n; weights pipelined ----
    for (int kc8 = 0; kc8 < 8; ++kc8) {
        int kc = kc8 * 32;
        bf16x8 wfc[4];
        for (int nf = 0; nf < 4; ++nf) wfc[nf] = wfp[nf];
        if (kc8 < 7)
            for (int nf = 0; nf < 4; ++nf)
                wfp[nf] = *reinterpret_cast<const bf16x8*>(W2T + (size_t)(mb + nf * 16 + cc) * HD + kc + 32 + quad * 8);
        for (int mf = 0; mf < 4; ++mf) {
            bf16x8 af = *reinterpret_cast<const bf16x8*>(&Ah[mf * 16 + cc][kc + quad * 8]);
            for (int nf = 0; nf < 4; ++nf)
                acc[mf][nf] = __builtin_amdgcn_mfma_f32_16x16x32_bf16(af, wfc[nf], acc[mf][nf], 0, 0, 0);
        }
    }

    // ---- epilogue 2: alpha partial = sum_n sigmoid(acc + u[seg][n]) * qw[n] ----
    float qwv[4];
    for (int nf = 0; nf < 4; ++nf) qwv[nf] = qw[mb + nf * 16 + cc];
    for (int mf = 0; mf < 4; ++mf)
        for (int r = 0; r < 4; ++r) {
            int token = mf * 16 + quad * 4 + r;
            const float* urow = u + (size_t)seg_s[token] * HD;
            float s = 0.f;
            for (int nf = 0; nf < 4; ++nf) {
                float g = acc[mf][nf][r] + urow[mb + nf * 16 + cc];
                g = 1.0f / (1.0f + __expf(-g));
                s += g * qwv[nf];
            }
            s += __shfl_xor(s, 1);
            s += __shfl_xor(s, 2);
            s += __shfl_xor(s, 4);
            s += __shfl_xor(s, 8);
            if (cc == 0) atomicAdd(&alpha_s[token], s);
        }
    __syncthreads();
    if (tid < BM) {
        int t = t0 + tid;
        if (t < T) alpha[t] = alpha_s[tid];
    }
}

// ---------------- weighted segment sum -> d_out ----------------
__global__ void hs_kernel(const float* __restrict__ hidden, const unsigned short* __restrict__ hb,
                          const float* __restrict__ alpha,
                          const int* __restrict__ offsets, float* __restrict__ out) {
    int b = blockIdx.x;
    int s = offsets[b], e = offsets[b + 1];
    int tid = threadIdx.x;
    __shared__ float al[256];
    for (int i = tid; i < e - s; i += 256) al[i] = alpha[s + i];
    __syncthreads();
    int g = tid >> 6, c = tid & 63;
    float4 acc = {0.f, 0.f, 0.f, 0.f};
    if (hb) {
        for (int t = s + g; t < e; t += 4) {
            float a = al[t - s];
            us4 v = *reinterpret_cast<const us4*>(hb + (size_t)t * HD + c * 4);
            acc.x += a * __uint_as_float(((unsigned)v[0]) << 16);
            acc.y += a * __uint_as_float(((unsigned)v[1]) << 16);
            acc.z += a * __uint_as_float(((unsigned)v[2]) << 16);
            acc.w += a * __uint_as_float(((unsigned)v[3]) << 16);
        }
    } else {
        for (int t = s + g; t < e; t += 4) {
            float a = al[t - s];
            const float4 v = *reinterpret_cast<const float4*>(hidden + (size_t)t * HD + c * 4);
            acc.x += a * v.x; acc.y += a * v.y; acc.z += a * v.z; acc.w += a * v.w;
        }
    }
    __shared__ float4 part[4][64];
    part[g][c] = acc;
    __syncthreads();
    if (g == 0) {
        float4 a0 = part[0][c], a1 = part[1][c], a2 = part[2][c], a3 = part[3][c];
        float4 m;
        m.x = a0.x + a1.x + a2.x + a3.x;
        m.y = a0.y + a1.y + a2.y + a3.y;
        m.z = a0.z + a1.z + a2.z + a3.z;
        m.w = a0.w + a1.w + a2.w + a3.w;
        *reinterpret_cast<float4*>(out + (size_t)b * HD + c * 4) = m;
    }
}

extern "C" void kernel_launch(void* const* d_in, const int* in_sizes, int n_in,
                              void* d_out, int out_size, void* d_ws, size_t ws_size,
                              hipStream_t stream) {
    (void)n_in; (void)out_size;
    const float* hidden    = (const float*)d_in[0];
    const float* pos_table = (const float*)d_in[1];
    const float* W_pos     = (const float*)d_in[2];
    const float* b_pos     = (const float*)d_in[3];
    const float* W1        = (const float*)d_in[4];
    const float* b1        = (const float*)d_in[5];
    const float* W2        = (const float*)d_in[6];
    const float* b2        = (const float*)d_in[7];
    const float* qw        = (const float*)d_in[8];
    const float* qb        = (const float*)d_in[9];
    const int* seq_len     = (const int*)d_in[10];
    const int* reverse_pos = (const int*)d_in[11];

    int T  = in_sizes[0] / HD;
    int B  = in_sizes[10];
    int NP = in_sizes[1] / HD;

    char* ws = (char*)d_ws;
    char* ws_end = ws + ws_size;
    auto carve = [&](size_t bytes) -> char* {
        char* p = ws;
        ws += (bytes + 255) & ~(size_t)255;
        return p;
    };
    int* offsets          = (int*)carve((size_t)(B + 1) * sizeof(int));
    int* seg              = (int*)carve((size_t)T * sizeof(int));
    unsigned short* meanb = (unsigned short*)carve((size_t)B * HD * 2);
    float* u              = (float*)carve((size_t)B * HD * sizeof(float));
    float* P2             = (float*)carve((size_t)NP * HD * sizeof(float));
    unsigned short* WphT  = (unsigned short*)carve((size_t)HD * HD * 2);
    unsigned short* WpbT  = (unsigned short*)carve((size_t)HD * HD * 2);
    unsigned short* W1T   = (unsigned short*)carve((size_t)HD * HD * 2);
    unsigned short* W2T   = (unsigned short*)carve((size_t)HD * HD * 2);
    float* alpha          = (float*)carve((size_t)T * sizeof(float));
    unsigned short* hb    = nullptr;
    if ((size_t)(ws_end - ws) >= (size_t)T * HD * 2 + 256)
        hb = (unsigned short*)carve((size_t)T * HD * 2);

    int nbu = (B + 15) / 16;
    int nbp = (NP + 15) / 16;

    scan_kernel<<<1, 256, 0, stream>>>(seq_len, offsets, B);
    transpose_kernel<<<HD, HD, 0, stream>>>(W_pos, W1, W2, WphT, WpbT, W1T, W2T);
    mean_kernel<<<B, 256, 0, stream>>>(hidden, offsets, meanb, hb, seg);
    small_gemm_kernel<<<nbu + nbp, 256, 0, stream>>>(meanb, B, nbu, pos_table, NP,
                                                     W1T, WpbT, b1, b2, b_pos, u, P2);
    main_kernel<<<(T + BM - 1) / BM, 256, 0, stream>>>(hidden, hb, T, WphT, W2T, P2, u, qw, qb,
                                                       reverse_pos, seg, alpha);
    hs_kernel<<<B, 256, 0, stream>>>(hidden, hb, alpha, offsets, (float*)d_out);
}